// Round 6
// baseline (735.727 us; speedup 1.0000x reference)
//
#include <hip/hip_runtime.h>

typedef float f4 __attribute__((ext_vector_type(4)));
typedef float f32x4 __attribute__((ext_vector_type(4)));
typedef short bf16x8 __attribute__((ext_vector_type(8)));
typedef unsigned short u16x8 __attribute__((ext_vector_type(8)));
typedef unsigned int u32x4 __attribute__((ext_vector_type(4)));

#define NPTS 262144
#define CDIM 48
#define DDIM 32
#define KDIM 4
#define G0 512
#define G1 512
#define G2 128

#define TILES_PER_BLOCK 2   // 128 points per tile, 2 tiles per block, one WB stage

// ws layout (ushort slots):
// [0, 18432)   : WB — bf16 MFMA B-fragments (36864 B)
//                frag f = (plane*2 + dtile)*6 + kt ; entry f*512 + lane*8 + j
//                value = tw[k] * feat_plane[id[k]][c][d],
//                kc = kt*32 + (lane>>4)*8 + j, k=kc/48, c=kc%48, d=dtile*16+(lane&15)
// T tables in bf16, layout [k][g][c]:
#define T0_OFF 18432                     // 4*512*48 = 98304
#define T1_OFF (18432 + 98304)           // 98304
#define T2_OFF (18432 + 2 * 98304)       // 4*128*48 = 24576

static __forceinline__ __device__ short f2b(float f) {
    __bf16 b = (__bf16)f;   // RNE
    return __builtin_bit_cast(short, b);
}
static __forceinline__ __device__ float b2f(unsigned short u) {
    return __builtin_bit_cast(float, ((unsigned int)u) << 16);
}

__global__ void pack_kernel(const int* __restrict__ topk_id,
                            const float* __restrict__ tw,
                            const float* __restrict__ line0,
                            const float* __restrict__ line1,
                            const float* __restrict__ line2,
                            const float* __restrict__ feat0,
                            const float* __restrict__ feat1,
                            const float* __restrict__ feat2,
                            unsigned short* __restrict__ ws) {
    int tid = blockIdx.x * blockDim.x + threadIdx.x;
    int stride = gridDim.x * blockDim.x;

    for (int idx = tid; idx < 3 * 2 * 6 * 64 * 8; idx += stride) {
        int j = idx & 7;
        int l = (idx >> 3) & 63;
        int kt = (idx >> 9) % 6;
        int t = (idx / 3072) % 2;
        int i = idx / 6144;
        int kc = kt * 32 + (l >> 4) * 8 + j;
        int k = kc / 48;
        int c = kc - k * 48;
        int d = t * 16 + (l & 15);
        const float* f = (i == 0) ? feat0 : (i == 1) ? feat1 : feat2;
        float val = tw[k] * f[((size_t)topk_id[k] * CDIM + c) * DDIM + d];
        ws[idx] = (unsigned short)f2b(val);
    }
    for (int idx = tid; idx < KDIM * G0 * CDIM; idx += stride) {
        int c = idx % CDIM;
        int g = (idx / CDIM) % G0;
        int k = idx / (CDIM * G0);
        int src = (topk_id[k] * CDIM + c) * G0 + g;
        ws[T0_OFF + idx] = (unsigned short)f2b(line0[src]);
        ws[T1_OFF + idx] = (unsigned short)f2b(line1[src]);
    }
    for (int idx = tid; idx < KDIM * G2 * CDIM; idx += stride) {
        int c = idx % CDIM;
        int g = (idx / CDIM) % G2;
        int k = idx / (CDIM * G2);
        ws[T2_OFF + idx] = (unsigned short)f2b(line2[(topk_id[k] * CDIM + c) * G2 + g]);
    }
}

struct LoadSet {
    u16x8 a0, b0, a1, b1, a2, b2;
};

__global__ __launch_bounds__(512, 4) void main_kernel(const float* __restrict__ pts,
                                                      const unsigned short* __restrict__ ws,
                                                      float* __restrict__ out) {
    __shared__ __align__(16) unsigned short sWB[18432];   // 36864 B
    {
        const u32x4* src = (const u32x4*)ws;
        u32x4* dst = (u32x4*)sWB;
        for (int i = threadIdx.x; i < 2304; i += 512) dst[i] = src[i];
    }
    __syncthreads();

    const int lane = threadIdx.x & 63;
    const int wave = threadIdx.x >> 6;
    const int row = lane & 15;
    const int h = lane >> 4;

    const unsigned short* T0 = ws + T0_OFF;
    const unsigned short* T1 = ws + T1_OFF;
    const unsigned short* T2 = ws + T2_OFF;
    const bf16x8* wb = (const bf16x8*)sWB;

    for (int tile = 0; tile < TILES_PER_BLOCK; ++tile) {
        const int base = (blockIdx.x * TILES_PER_BLOCK + tile) * 128 + wave * 16;
        const int p = base + row;

        const float px = pts[p * 3 + 0];
        const float py = pts[p * 3 + 1];
        const float pz = pts[p * 3 + 2];

        float pos0 = (px + 1.0f) * (0.5f * (float)(G0 - 1));
        int i00 = min(max((int)floorf(pos0), 0), G0 - 2);
        float w0 = pos0 - (float)i00, om0 = 1.0f - w0;

        float pos1 = (py + 1.0f) * (0.5f * (float)(G1 - 1));
        int i01 = min(max((int)floorf(pos1), 0), G1 - 2);
        float w1 = pos1 - (float)i01, om1 = 1.0f - w1;

        float pos2 = (pz + 1.0f) * (0.5f * (float)(G2 - 1));
        int i02 = min(max((int)floorf(pos2), 0), G2 - 2);
        float w2 = pos2 - (float)i02, om2 = 1.0f - w2;

#define LOADKT(S, KT) {                                                        \
        int kc_ = (KT) * 32 + h * 8;                                           \
        int k_ = kc_ / 48;                                                     \
        int c_ = kc_ - k_ * 48;                                                \
        const unsigned short* t0_ = T0 + (k_ * G0 + i00) * CDIM + c_;          \
        const unsigned short* t1_ = T1 + (k_ * G1 + i01) * CDIM + c_;          \
        const unsigned short* t2_ = T2 + (k_ * G2 + i02) * CDIM + c_;          \
        (S).a0 = *(const u16x8*)t0_;  (S).b0 = *(const u16x8*)(t0_ + CDIM);    \
        (S).a1 = *(const u16x8*)t1_;  (S).b1 = *(const u16x8*)(t1_ + CDIM);    \
        (S).a2 = *(const u16x8*)t2_;  (S).b2 = *(const u16x8*)(t2_ + CDIM); }

        f32x4 acc00 = {0.f, 0.f, 0.f, 0.f}, acc01 = acc00;
        f32x4 acc10 = acc00, acc11 = acc00;
        f32x4 acc20 = acc00, acc21 = acc00;

        LoadSet ld[2];
        LOADKT(ld[0], 0);

#pragma unroll
        for (int kt = 0; kt < 6; ++kt) {
            if (kt < 5) LOADKT(ld[(kt + 1) & 1], kt + 1);
            // pin: next-kt loads stay issued ABOVE current-kt compute
            __builtin_amdgcn_sched_barrier(0);

            const LoadSet& cur = ld[kt & 1];
            bf16x8 a01, a02, a12;
#pragma unroll
            for (int j = 0; j < 8; ++j) {
                float x0 = b2f(cur.a0[j]) * om0 + b2f(cur.b0[j]) * w0;
                float x1 = b2f(cur.a1[j]) * om1 + b2f(cur.b1[j]) * w1;
                float x2 = b2f(cur.a2[j]) * om2 + b2f(cur.b2[j]) * w2;
                a01[j] = f2b(x0 * x1);
                a02[j] = f2b(x0 * x2);
                a12[j] = f2b(x1 * x2);
            }

            acc00 = __builtin_amdgcn_mfma_f32_16x16x32_bf16(a01, wb[(0 * 6 + kt) * 64 + lane], acc00, 0, 0, 0);
            acc01 = __builtin_amdgcn_mfma_f32_16x16x32_bf16(a01, wb[(1 * 6 + kt) * 64 + lane], acc01, 0, 0, 0);
            acc10 = __builtin_amdgcn_mfma_f32_16x16x32_bf16(a02, wb[(2 * 6 + kt) * 64 + lane], acc10, 0, 0, 0);
            acc11 = __builtin_amdgcn_mfma_f32_16x16x32_bf16(a02, wb[(3 * 6 + kt) * 64 + lane], acc11, 0, 0, 0);
            acc20 = __builtin_amdgcn_mfma_f32_16x16x32_bf16(a12, wb[(4 * 6 + kt) * 64 + lane], acc20, 0, 0, 0);
            acc21 = __builtin_amdgcn_mfma_f32_16x16x32_bf16(a12, wb[(5 * 6 + kt) * 64 + lane], acc21, 0, 0, 0);
        }
#undef LOADKT

        // C layout (m89-verified): col = lane&15, row = (lane>>4)*4 + reg
        // Non-temporal: output is write-once, keep it out of L2 so the
        // T-tables / WB stay resident.
#pragma unroll
        for (int r = 0; r < 4; ++r) {
            size_t o = (size_t)(base + h * 4 + r) * 96 + row;
            __builtin_nontemporal_store(acc00[r], &out[o + 0]);
            __builtin_nontemporal_store(acc01[r], &out[o + 16]);
            __builtin_nontemporal_store(acc10[r], &out[o + 32]);
            __builtin_nontemporal_store(acc11[r], &out[o + 48]);
            __builtin_nontemporal_store(acc20[r], &out[o + 64]);
            __builtin_nontemporal_store(acc21[r], &out[o + 80]);
        }
    }
}

extern "C" void kernel_launch(void* const* d_in, const int* in_sizes, int n_in,
                              void* d_out, int out_size, void* d_ws, size_t ws_size,
                              hipStream_t stream) {
    const float* pts = (const float*)d_in[0];
    const int* topk_id = (const int*)d_in[1];
    const float* tw = (const float*)d_in[2];
    const float* line0 = (const float*)d_in[3];
    const float* line1 = (const float*)d_in[4];
    const float* line2 = (const float*)d_in[5];
    const float* feat0 = (const float*)d_in[6];
    const float* feat1 = (const float*)d_in[7];
    const float* feat2 = (const float*)d_in[8];
    float* out = (float*)d_out;
    unsigned short* ws = (unsigned short*)d_ws;

    pack_kernel<<<512, 256, 0, stream>>>(topk_id, tw, line0, line1, line2,
                                         feat0, feat1, feat2, ws);
    main_kernel<<<NPTS / (128 * TILES_PER_BLOCK), 512, 0, stream>>>(pts, ws, out);
}

// Round 7
// 246.789 us; speedup vs baseline: 2.9812x; 2.9812x over previous
//
#include <hip/hip_runtime.h>

typedef float f4 __attribute__((ext_vector_type(4)));
typedef float f32x4 __attribute__((ext_vector_type(4)));
typedef short bf16x8 __attribute__((ext_vector_type(8)));
typedef unsigned short u16x8 __attribute__((ext_vector_type(8)));
typedef unsigned int u32x4 __attribute__((ext_vector_type(4)));

#define NPTS 262144
#define CDIM 48
#define DDIM 32
#define KDIM 4
#define G0 512
#define G1 512
#define G2 128

// ws layout (ushort slots):
// [0, 18432)   : WB — bf16 MFMA B-fragments (36864 B)
//                frag f = (plane*2 + dtile)*6 + kt ; entry f*512 + lane*8 + j
//                value = tw[k] * feat_plane[id[k]][c][d],
//                kc = kt*32 + (lane>>4)*8 + j, k=kc/48, c=kc%48, d=dtile*16+(lane&15)
// T tables in bf16, layout [k][g][c]:
#define T0_OFF 18432                     // 4*512*48 = 98304
#define T1_OFF (18432 + 98304)           // 98304
#define T2_OFF (18432 + 2 * 98304)       // 4*128*48 = 24576

static __forceinline__ __device__ short f2b(float f) {
    __bf16 b = (__bf16)f;   // RNE
    return __builtin_bit_cast(short, b);
}
static __forceinline__ __device__ float b2f(unsigned short u) {
    return __builtin_bit_cast(float, ((unsigned int)u) << 16);
}

__global__ void pack_kernel(const int* __restrict__ topk_id,
                            const float* __restrict__ tw,
                            const float* __restrict__ line0,
                            const float* __restrict__ line1,
                            const float* __restrict__ line2,
                            const float* __restrict__ feat0,
                            const float* __restrict__ feat1,
                            const float* __restrict__ feat2,
                            unsigned short* __restrict__ ws) {
    int tid = blockIdx.x * blockDim.x + threadIdx.x;
    int stride = gridDim.x * blockDim.x;

    for (int idx = tid; idx < 3 * 2 * 6 * 64 * 8; idx += stride) {
        int j = idx & 7;
        int l = (idx >> 3) & 63;
        int kt = (idx >> 9) % 6;
        int t = (idx / 3072) % 2;
        int i = idx / 6144;
        int kc = kt * 32 + (l >> 4) * 8 + j;
        int k = kc / 48;
        int c = kc - k * 48;
        int d = t * 16 + (l & 15);
        const float* f = (i == 0) ? feat0 : (i == 1) ? feat1 : feat2;
        float val = tw[k] * f[((size_t)topk_id[k] * CDIM + c) * DDIM + d];
        ws[idx] = (unsigned short)f2b(val);
    }
    for (int idx = tid; idx < KDIM * G0 * CDIM; idx += stride) {
        int c = idx % CDIM;
        int g = (idx / CDIM) % G0;
        int k = idx / (CDIM * G0);
        int src = (topk_id[k] * CDIM + c) * G0 + g;
        ws[T0_OFF + idx] = (unsigned short)f2b(line0[src]);
        ws[T1_OFF + idx] = (unsigned short)f2b(line1[src]);
    }
    for (int idx = tid; idx < KDIM * G2 * CDIM; idx += stride) {
        int c = idx % CDIM;
        int g = (idx / CDIM) % G2;
        int k = idx / (CDIM * G2);
        ws[T2_OFF + idx] = (unsigned short)f2b(line2[(topk_id[k] * CDIM + c) * G2 + g]);
    }
}

struct LoadSet {
    u16x8 a0, b0, a1, b1, a2, b2;
};

__global__ __launch_bounds__(512, 3) void main_kernel(const float* __restrict__ pts,
                                                      const unsigned short* __restrict__ ws,
                                                      float* __restrict__ out) {
    __shared__ __align__(16) unsigned short sWB[18432];   // 36864 B
    {
        const u32x4* src = (const u32x4*)ws;
        u32x4* dst = (u32x4*)sWB;
        for (int i = threadIdx.x; i < 2304; i += 512) dst[i] = src[i];
    }
    __syncthreads();

    const int lane = threadIdx.x & 63;
    const int wave = threadIdx.x >> 6;
    const int row = lane & 15;
    const int h = lane >> 4;
    const int base = blockIdx.x * 128 + wave * 16;
    const int p = base + row;

    const float px = pts[p * 3 + 0];
    const float py = pts[p * 3 + 1];
    const float pz = pts[p * 3 + 2];

    float pos0 = (px + 1.0f) * (0.5f * (float)(G0 - 1));
    int i00 = min(max((int)floorf(pos0), 0), G0 - 2);
    float w0 = pos0 - (float)i00, om0 = 1.0f - w0;

    float pos1 = (py + 1.0f) * (0.5f * (float)(G1 - 1));
    int i01 = min(max((int)floorf(pos1), 0), G1 - 2);
    float w1 = pos1 - (float)i01, om1 = 1.0f - w1;

    float pos2 = (pz + 1.0f) * (0.5f * (float)(G2 - 1));
    int i02 = min(max((int)floorf(pos2), 0), G2 - 2);
    float w2 = pos2 - (float)i02, om2 = 1.0f - w2;

    const unsigned short* T0 = ws + T0_OFF;
    const unsigned short* T1 = ws + T1_OFF;
    const unsigned short* T2 = ws + T2_OFF;
    const bf16x8* wb = (const bf16x8*)sWB;

#define LOADKT(S, KT) {                                                        \
        int kc_ = (KT) * 32 + h * 8;                                           \
        int k_ = kc_ / 48;                                                     \
        int c_ = kc_ - k_ * 48;                                                \
        const unsigned short* t0_ = T0 + (k_ * G0 + i00) * CDIM + c_;          \
        const unsigned short* t1_ = T1 + (k_ * G1 + i01) * CDIM + c_;          \
        const unsigned short* t2_ = T2 + (k_ * G2 + i02) * CDIM + c_;          \
        (S).a0 = *(const u16x8*)t0_;  (S).b0 = *(const u16x8*)(t0_ + CDIM);    \
        (S).a1 = *(const u16x8*)t1_;  (S).b1 = *(const u16x8*)(t1_ + CDIM);    \
        (S).a2 = *(const u16x8*)t2_;  (S).b2 = *(const u16x8*)(t2_ + CDIM); }

    f32x4 acc00 = {0.f, 0.f, 0.f, 0.f}, acc01 = acc00;
    f32x4 acc10 = acc00, acc11 = acc00;
    f32x4 acc20 = acc00, acc21 = acc00;

    // 3-deep rolling window: 18 independent gathers in flight before the
    // first compute; each kt refills its slot with kt+3's loads. The
    // sched_barrier(0) pins the refill ABOVE the next kt's compute so the
    // scheduler cannot re-serialize the pipeline (rounds 4/6 failure mode).
    LoadSet ld0, ld1, ld2;
    LOADKT(ld0, 0);
    LOADKT(ld1, 1);
    LOADKT(ld2, 2);
    __builtin_amdgcn_sched_barrier(0);

#define COMPUTEKT(S, KT) {                                                     \
        bf16x8 a01, a02, a12;                                                  \
        _Pragma("unroll")                                                      \
        for (int j = 0; j < 8; ++j) {                                          \
            float x0 = b2f((S).a0[j]) * om0 + b2f((S).b0[j]) * w0;             \
            float x1 = b2f((S).a1[j]) * om1 + b2f((S).b1[j]) * w1;             \
            float x2 = b2f((S).a2[j]) * om2 + b2f((S).b2[j]) * w2;             \
            a01[j] = f2b(x0 * x1);                                             \
            a02[j] = f2b(x0 * x2);                                             \
            a12[j] = f2b(x1 * x2);                                             \
        }                                                                      \
        acc00 = __builtin_amdgcn_mfma_f32_16x16x32_bf16(a01, wb[(0 * 6 + (KT)) * 64 + lane], acc00, 0, 0, 0); \
        acc01 = __builtin_amdgcn_mfma_f32_16x16x32_bf16(a01, wb[(1 * 6 + (KT)) * 64 + lane], acc01, 0, 0, 0); \
        acc10 = __builtin_amdgcn_mfma_f32_16x16x32_bf16(a02, wb[(2 * 6 + (KT)) * 64 + lane], acc10, 0, 0, 0); \
        acc11 = __builtin_amdgcn_mfma_f32_16x16x32_bf16(a02, wb[(3 * 6 + (KT)) * 64 + lane], acc11, 0, 0, 0); \
        acc20 = __builtin_amdgcn_mfma_f32_16x16x32_bf16(a12, wb[(4 * 6 + (KT)) * 64 + lane], acc20, 0, 0, 0); \
        acc21 = __builtin_amdgcn_mfma_f32_16x16x32_bf16(a12, wb[(5 * 6 + (KT)) * 64 + lane], acc21, 0, 0, 0); }

    COMPUTEKT(ld0, 0);
    LOADKT(ld0, 3);
    __builtin_amdgcn_sched_barrier(0);

    COMPUTEKT(ld1, 1);
    LOADKT(ld1, 4);
    __builtin_amdgcn_sched_barrier(0);

    COMPUTEKT(ld2, 2);
    LOADKT(ld2, 5);
    __builtin_amdgcn_sched_barrier(0);

    COMPUTEKT(ld0, 3);
    COMPUTEKT(ld1, 4);
    COMPUTEKT(ld2, 5);

#undef LOADKT
#undef COMPUTEKT

    // C layout (m89-verified): col = lane&15, row = (lane>>4)*4 + reg
#pragma unroll
    for (int r = 0; r < 4; ++r) {
        size_t o = (size_t)(base + h * 4 + r) * 96 + row;
        out[o + 0]  = acc00[r];
        out[o + 16] = acc01[r];
        out[o + 32] = acc10[r];
        out[o + 48] = acc11[r];
        out[o + 64] = acc20[r];
        out[o + 80] = acc21[r];
    }
}

extern "C" void kernel_launch(void* const* d_in, const int* in_sizes, int n_in,
                              void* d_out, int out_size, void* d_ws, size_t ws_size,
                              hipStream_t stream) {
    const float* pts = (const float*)d_in[0];
    const int* topk_id = (const int*)d_in[1];
    const float* tw = (const float*)d_in[2];
    const float* line0 = (const float*)d_in[3];
    const float* line1 = (const float*)d_in[4];
    const float* line2 = (const float*)d_in[5];
    const float* feat0 = (const float*)d_in[6];
    const float* feat1 = (const float*)d_in[7];
    const float* feat2 = (const float*)d_in[8];
    float* out = (float*)d_out;
    unsigned short* ws = (unsigned short*)d_ws;

    pack_kernel<<<512, 256, 0, stream>>>(topk_id, tw, line0, line1, line2,
                                         feat0, feat1, feat2, ws);
    main_kernel<<<NPTS / 128, 512, 0, stream>>>(pts, ws, out);
}

// Round 8
// 97.866 us; speedup vs baseline: 7.5177x; 2.5217x over previous
//
#include <hip/hip_runtime.h>

typedef float f4 __attribute__((ext_vector_type(4)));
typedef float f32x4 __attribute__((ext_vector_type(4)));
typedef short bf16x8 __attribute__((ext_vector_type(8)));
typedef unsigned short u16x8 __attribute__((ext_vector_type(8)));
typedef unsigned int u32x4 __attribute__((ext_vector_type(4)));

#define NPTS 262144
#define CDIM 48
#define DDIM 32
#define KDIM 4
#define G0 512
#define G1 512
#define G2 128

// ws layout (ushort slots):
// [0, 18432)   : WB — bf16 MFMA fragments (36864 B)
//                frag f = (plane*2 + dtile)*6 + kt ; entry f*512 + lane*8 + j
//                value = tw[k] * feat_plane[id[k]][c][d],
//                kc = kt*32 + (lane>>4)*8 + j, k=kc/48, c=kc%48, d=dtile*16+(lane&15)
// T tables in bf16, layout [k][g][c]:
#define T0_OFF 18432                     // 4*512*48 = 98304
#define T1_OFF (18432 + 98304)           // 98304
#define T2_OFF (18432 + 2 * 98304)       // 4*128*48 = 24576

static __forceinline__ __device__ short f2b(float f) {
    __bf16 b = (__bf16)f;   // RNE
    return __builtin_bit_cast(short, b);
}
static __forceinline__ __device__ float b2f(unsigned short u) {
    return __builtin_bit_cast(float, ((unsigned int)u) << 16);
}

__global__ void pack_kernel(const int* __restrict__ topk_id,
                            const float* __restrict__ tw,
                            const float* __restrict__ line0,
                            const float* __restrict__ line1,
                            const float* __restrict__ line2,
                            const float* __restrict__ feat0,
                            const float* __restrict__ feat1,
                            const float* __restrict__ feat2,
                            unsigned short* __restrict__ ws) {
    int tid = blockIdx.x * blockDim.x + threadIdx.x;
    int stride = gridDim.x * blockDim.x;

    for (int idx = tid; idx < 3 * 2 * 6 * 64 * 8; idx += stride) {
        int j = idx & 7;
        int l = (idx >> 3) & 63;
        int kt = (idx >> 9) % 6;
        int t = (idx / 3072) % 2;
        int i = idx / 6144;
        int kc = kt * 32 + (l >> 4) * 8 + j;
        int k = kc / 48;
        int c = kc - k * 48;
        int d = t * 16 + (l & 15);
        const float* f = (i == 0) ? feat0 : (i == 1) ? feat1 : feat2;
        float val = tw[k] * f[((size_t)topk_id[k] * CDIM + c) * DDIM + d];
        ws[idx] = (unsigned short)f2b(val);
    }
    for (int idx = tid; idx < KDIM * G0 * CDIM; idx += stride) {
        int c = idx % CDIM;
        int g = (idx / CDIM) % G0;
        int k = idx / (CDIM * G0);
        int src = (topk_id[k] * CDIM + c) * G0 + g;
        ws[T0_OFF + idx] = (unsigned short)f2b(line0[src]);
        ws[T1_OFF + idx] = (unsigned short)f2b(line1[src]);
    }
    for (int idx = tid; idx < KDIM * G2 * CDIM; idx += stride) {
        int c = idx % CDIM;
        int g = (idx / CDIM) % G2;
        int k = idx / (CDIM * G2);
        ws[T2_OFF + idx] = (unsigned short)f2b(line2[(topk_id[k] * CDIM + c) * G2 + g]);
    }
}

__global__ __launch_bounds__(512, 4) void main_kernel(const float* __restrict__ pts,
                                                      const unsigned short* __restrict__ ws,
                                                      float* __restrict__ out) {
    __shared__ __align__(16) unsigned short sWB[18432];   // 36864 B
    {
        const u32x4* src = (const u32x4*)ws;
        u32x4* dst = (u32x4*)sWB;
        for (int i = threadIdx.x; i < 2304; i += 512) dst[i] = src[i];
    }
    __syncthreads();

    const int lane = threadIdx.x & 63;
    const int wave = threadIdx.x >> 6;
    const int row = lane & 15;     // point within the wave's 16-point tile
    const int h = lane >> 4;       // k-chunk selector (and d-subblock at epilogue)
    const int base = blockIdx.x * 128 + wave * 16;
    const int p = base + row;

    const float px = pts[p * 3 + 0];
    const float py = pts[p * 3 + 1];
    const float pz = pts[p * 3 + 2];

    float pos0 = (px + 1.0f) * (0.5f * (float)(G0 - 1));
    int i00 = min(max((int)floorf(pos0), 0), G0 - 2);
    float w0 = pos0 - (float)i00, om0 = 1.0f - w0;

    float pos1 = (py + 1.0f) * (0.5f * (float)(G1 - 1));
    int i01 = min(max((int)floorf(pos1), 0), G1 - 2);
    float w1 = pos1 - (float)i01, om1 = 1.0f - w1;

    float pos2 = (pz + 1.0f) * (0.5f * (float)(G2 - 1));
    int i02 = min(max((int)floorf(pos2), 0), G2 - 2);
    float w2 = pos2 - (float)i02, om2 = 1.0f - w2;

    const unsigned short* T0 = ws + T0_OFF;
    const unsigned short* T1 = ws + T1_OFF;
    const unsigned short* T2 = ws + T2_OFF;
    const bf16x8* wb = (const bf16x8*)sWB;

    f32x4 acc00 = {0.f, 0.f, 0.f, 0.f}, acc01 = acc00;
    f32x4 acc10 = acc00, acc11 = acc00;
    f32x4 acc20 = acc00, acc21 = acc00;

#pragma unroll
    for (int kt = 0; kt < 6; ++kt) {
        int kc = kt * 32 + h * 8;
        int k = kc / 48;
        int c = kc - k * 48;

        // one 16B load = the lane's full 8-value k-slot (bf16)
        const unsigned short* t0 = T0 + (k * G0 + i00) * CDIM + c;
        const unsigned short* t1 = T1 + (k * G1 + i01) * CDIM + c;
        const unsigned short* t2 = T2 + (k * G2 + i02) * CDIM + c;

        u16x8 a0 = *(const u16x8*)t0, b0 = *(const u16x8*)(t0 + CDIM);
        u16x8 a1 = *(const u16x8*)t1, b1 = *(const u16x8*)(t1 + CDIM);
        u16x8 a2 = *(const u16x8*)t2, b2 = *(const u16x8*)(t2 + CDIM);

        bf16x8 a01, a02, a12;
#pragma unroll
        for (int j = 0; j < 8; ++j) {
            float x0 = b2f(a0[j]) * om0 + b2f(b0[j]) * w0;
            float x1 = b2f(a1[j]) * om1 + b2f(b1[j]) * w1;
            float x2 = b2f(a2[j]) * om2 + b2f(b2[j]) * w2;
            a01[j] = f2b(x0 * x1);
            a02[j] = f2b(x0 * x2);
            a12[j] = f2b(x1 * x2);
        }

        // OPERANDS SWAPPED vs R5: wb as A, products as B -> C^T.
        // A layout (row=lane&15 -> d_local) and B layout (col=lane&15 -> point)
        // are both already HW-proven by the R5 kernel; C/D (m89): col=lane&15
        // = point, row=(lane>>4)*4+reg = d_local.
        acc00 = __builtin_amdgcn_mfma_f32_16x16x32_bf16(wb[(0 * 6 + kt) * 64 + lane], a01, acc00, 0, 0, 0);
        acc01 = __builtin_amdgcn_mfma_f32_16x16x32_bf16(wb[(1 * 6 + kt) * 64 + lane], a01, acc01, 0, 0, 0);
        acc10 = __builtin_amdgcn_mfma_f32_16x16x32_bf16(wb[(2 * 6 + kt) * 64 + lane], a02, acc10, 0, 0, 0);
        acc11 = __builtin_amdgcn_mfma_f32_16x16x32_bf16(wb[(3 * 6 + kt) * 64 + lane], a02, acc11, 0, 0, 0);
        acc20 = __builtin_amdgcn_mfma_f32_16x16x32_bf16(wb[(4 * 6 + kt) * 64 + lane], a12, acc20, 0, 0, 0);
        acc21 = __builtin_amdgcn_mfma_f32_16x16x32_bf16(wb[(5 * 6 + kt) * 64 + lane], a12, acc21, 0, 0, 0);
    }

    // Epilogue: lane owns point n = base+row, d-block h*4..h*4+3 of each
    // 16-wide dtile -> 6 float4 stores, 64B-contiguous per point per
    // instruction (full-line write-combining; was 24 scalar stores).
    {
        float* o = out + (size_t)(base + row) * 96 + h * 4;
        *(f4*)(o + 0)  = acc00;
        *(f4*)(o + 16) = acc01;
        *(f4*)(o + 32) = acc10;
        *(f4*)(o + 48) = acc11;
        *(f4*)(o + 64) = acc20;
        *(f4*)(o + 80) = acc21;
    }
}

extern "C" void kernel_launch(void* const* d_in, const int* in_sizes, int n_in,
                              void* d_out, int out_size, void* d_ws, size_t ws_size,
                              hipStream_t stream) {
    const float* pts = (const float*)d_in[0];
    const int* topk_id = (const int*)d_in[1];
    const float* tw = (const float*)d_in[2];
    const float* line0 = (const float*)d_in[3];
    const float* line1 = (const float*)d_in[4];
    const float* line2 = (const float*)d_in[5];
    const float* feat0 = (const float*)d_in[6];
    const float* feat1 = (const float*)d_in[7];
    const float* feat2 = (const float*)d_in[8];
    float* out = (float*)d_out;
    unsigned short* ws = (unsigned short*)d_ws;

    pack_kernel<<<512, 256, 0, stream>>>(topk_id, tw, line0, line1, line2,
                                         feat0, feat1, feat2, ws);
    main_kernel<<<NPTS / 128, 512, 0, stream>>>(pts, ws, out);
}